// Round 4
// baseline (1105.756 us; speedup 1.0000x reference)
//
#include <hip/hip_runtime.h>

// Problem constants
#define NATOMS 4096
#define NTYPES 2
#define NA 2048
#define MAXNB 100
#define JN 200          // neighbors per atom
#define TFD 4
#define E0 25           // emb hidden 0
#define E1 50           // emb hidden 1
#define GD 100          // GDIM
#define M2D 16
#define DD 1600         // D = M2*GDIM
#define FHD 240
#define INV200 (1.0f/200.0f)

// Output layout (floats): Etot@0 (1), Ei@1 (4096), F@4097 (12288), Virial@16385 (9)
#define OUT_EI 1
#define OUT_F 4097
#define OUT_V 16385

// Workspace layout (floats)
#define WS_DRQ 0L                 // 4096*1600  (dr, later overwritten by Q)
#define WS_XA 6553600L            // 4096*400
#define WS_P 8192000L             // 4096*400  (g-major float4: [n][g][c])
#define WS_FH0 9830400L           // 4096*240
#define WS_FH1 10813440L          // 4096*240
#define WS_DH0G 11796480L         // 4096*240
#define WS_FW0T 12779520L         // 2*240*1600

// G(s) lookup table: per type, per knot, (G_g, dG_g/ds) for g in [0,100).
// Embedding-net input is [s, temb(type)] with temb constant per type, so G is a
// 1-D function of s per type. Cubic Hermite on 2048 knots over [-8,8]:
// error ~ h^4/384 * f'''' ~ 1e-7 (max|s| of 819200 N(0,1) draws ~ 5.2).
#define NK 2048
#define S_MIN (-8.0f)
#define S_H 0.0078125f      // 16/2048
#define S_INVH 128.0f
__device__ float2 g_tab[NTYPES * NK * GD];

__device__ __forceinline__ float ftanh(float x) {
    float ax = fabsf(x);
    float e = __expf(-2.0f * ax);
    float t = (1.0f - e) / (1.0f + e);
    return copysignf(t, x);
}

// ---------------- setup: transpose fw0 ----------------
__global__ void k_setup(const float* __restrict__ fw0, float* __restrict__ fw0T) {
    int idx = blockIdx.x * 256 + threadIdx.x;
    if (idx < NTYPES * DD * FHD) {
        int t = idx / (DD * FHD);
        int r = idx % (DD * FHD);
        int o = r / DD, d = r % DD;
        fw0T[idx] = fw0[(long)t * DD * FHD + (long)d * FHD + o];
    }
}

// ---------------- table build: one thread per (type, knot) ----------------
__global__ __launch_bounds__(64) void k_table(
    const float* __restrict__ ew0, const float* __restrict__ eb0,
    const float* __restrict__ ew1, const float* __restrict__ eb1,
    const float* __restrict__ ew2, const float* __restrict__ eb2,
    const float* __restrict__ tv)
{
    int idx = blockIdx.x * 64 + threadIdx.x;
    if (idx >= NTYPES * NK) return;
    int t = idx / NK, i = idx % NK;
    float s = S_MIN + (float)i * S_H;

    float h0[E0], t0[E0];
#pragma unroll
    for (int k = 0; k < E0; ++k) {
        float c = eb0[k];
#pragma unroll
        for (int f = 0; f < TFD; ++f) c = fmaf(tv[t * TFD + f], ew0[(1 + f) * E0 + k], c);
        float h = ftanh(fmaf(s, ew0[k], c));
        h0[k] = h;
        t0[k] = (1.f - h * h) * ew0[k];
    }
    float h1[E1], v1[E1];
#pragma unroll
    for (int l = 0; l < E1; ++l) {
        float acc = eb1[l], dacc = 0.f;
#pragma unroll
        for (int k = 0; k < E0; ++k) {
            float w = ew1[k * E1 + l];
            acc = fmaf(h0[k], w, acc);
            dacc = fmaf(t0[k], w, dacc);
        }
        float h = ftanh(acc);
        h1[l] = h;
        v1[l] = (1.f - h * h) * dacc;
    }
    for (int g = 0; g < GD; ++g) {
        float acc = eb2[g], dacc = 0.f;
#pragma unroll
        for (int l = 0; l < E1; ++l) {
            float w = ew2[l * GD + g];
            acc = fmaf(h1[l], w, acc);
            dacc = fmaf(v1[l], w, dacc);
        }
        float G = ftanh(acc);
        g_tab[(long)(t * NK + i) * GD + g] = make_float2(G, (1.f - G * G) * dacc);
    }
}

// Hermite basis for G: c00..c11 (h folded into c10/c11).
// For dG: d00 = (6u^2-6u)/h, d01 = -d00, d10 = 3u^2-4u+1, d11 = 3u^2-2u.
__device__ __forceinline__ void hermite_basis(float s, int tau, const float2** r0, const float2** r1,
                                              float& c00, float& c01, float& c10, float& c11,
                                              float& d00, float& d10, float& d11) {
    float x = (s - S_MIN) * S_INVH;
    x = fminf(fmaxf(x, 0.f), (float)(NK - 1) - 1e-3f);
    int i = (int)x;
    float u = x - (float)i;
    float um = 1.f - u;
    c00 = (1.f + 2.f * u) * um * um;
    c01 = u * u * (3.f - 2.f * u);
    c10 = S_H * u * um * um;
    c11 = S_H * u * u * (u - 1.f);
    d00 = (6.f * u * u - 6.f * u) * S_INVH;
    d10 = fmaf(3.f * u, u, fmaf(-4.f, u, 1.f));
    d11 = fmaf(3.f * u, u, -2.f * u);
    const float2* base = g_tab + (long)(tau * NK + i) * GD;
    *r0 = base;
    *r1 = base + GD;
}

// ---------------- K1: per-atom G (table) -> xa -> dr ----------------
#define GCH 25
__global__ __launch_bounds__(256) void k1_emb(
    const float* __restrict__ Ri,
    float* __restrict__ dr_ws, float* __restrict__ xa_ws)
{
    __shared__ float a4s[JN * 4];
    __shared__ float Gs[GCH * 201];
    __shared__ float xas[4 * GD];
    __shared__ float red[256];

    int tid = threadIdx.x;
    int n = blockIdx.x;

    float4 a = make_float4(0.f, 0.f, 0.f, 0.f);
    const float2 *row0 = nullptr, *row1 = nullptr;
    float c00 = 0.f, c01 = 0.f, c10 = 0.f, c11 = 0.f, d00, d10, d11;
    if (tid < JN) {
        a = ((const float4*)Ri)[(long)n * JN + tid];
        ((float4*)a4s)[tid] = a;
        hermite_basis(a.x, tid / MAXNB, &row0, &row1, c00, c01, c10, c11, d00, d10, d11);
    }
    __syncthreads();

    int gl_r = tid % GCH;
    int c_r = (tid / GCH) % 4;
    int jh_r = tid / 100;

    for (int cc = 0; cc < 4; ++cc) {
        int g0 = cc * GCH;
        if (tid < JN) {
#pragma unroll
            for (int gl = 0; gl < GCH; ++gl) {
                float2 r0 = row0[g0 + gl], r1 = row1[g0 + gl];
                Gs[gl * 201 + tid] = r0.x * c00 + r1.x * c01 + r0.y * c10 + r1.y * c11;
            }
        }
        __syncthreads();
        float s_ = 0.f;
        if (tid < JN) {
            const float* grow = &Gs[gl_r * 201 + jh_r * 100];
            const float* arow = &a4s[jh_r * 400 + c_r];
            for (int jj = 0; jj < 100; ++jj)
                s_ = fmaf(arow[jj * 4], grow[jj], s_);
        }
        red[tid] = s_;
        __syncthreads();
        if (tid < 100) {
            int c = tid / GCH, gl = tid % GCH;
            xas[c * GD + g0 + gl] = (red[tid] + red[tid + 100]) * INV200;
        }
        __syncthreads();
    }

    for (int i = tid; i < 4 * GD; i += 256) xa_ws[(long)n * 400 + i] = xas[i];
    for (int i = tid; i < DD; i += 256) {
        int gg = i / M2D, m = i % M2D;
        float v = 0.f;
#pragma unroll
        for (int c = 0; c < 4; ++c) v = fmaf(xas[c * GD + gg], xas[c * GD + m], v);
        dr_ws[(long)n * DD + i] = v;
    }
}

// ---------------- generic tiled fp32 GEMM: C = act(A@B + bias), per-type batch z ----------------
__global__ __launch_bounds__(256) void gemm_kernel(
    const float* __restrict__ Ab, const float* __restrict__ Bb,
    const float* __restrict__ biasb, float* __restrict__ Cb,
    int M, int Nn, int K, long sA, long sB, long sBias, long sC, int do_tanh)
{
    int t = blockIdx.z;
    const float* A = Ab + (long)t * sA;
    const float* B = Bb + (long)t * sB;
    const float* bias = biasb ? (biasb + (long)t * sBias) : nullptr;
    float* C = Cb + (long)t * sC;

    __shared__ float As[16 * 64];
    __shared__ float Bs[16 * 64];

    int tid = threadIdx.x;
    int n0 = blockIdx.x * 64;
    int m0 = blockIdx.y * 64;
    int tx = tid % 16, ty = tid / 16;

    float acc[4][4];
#pragma unroll
    for (int i = 0; i < 4; ++i)
#pragma unroll
        for (int j = 0; j < 4; ++j) acc[i][j] = 0.f;

    int a_m = tid / 4;
    int a_k = (tid % 4) * 4;
    int b_k = tid / 16;
    int b_n = (tid % 16) * 4;

    for (int k0 = 0; k0 < K; k0 += 16) {
        float4 av = *(const float4*)&A[(long)(m0 + a_m) * K + k0 + a_k];
        float4 bv = make_float4(0.f, 0.f, 0.f, 0.f);
        if (n0 + b_n < Nn) bv = *(const float4*)&B[(long)(k0 + b_k) * Nn + n0 + b_n];
        __syncthreads();
        As[(a_k + 0) * 64 + a_m] = av.x;
        As[(a_k + 1) * 64 + a_m] = av.y;
        As[(a_k + 2) * 64 + a_m] = av.z;
        As[(a_k + 3) * 64 + a_m] = av.w;
        *(float4*)&Bs[b_k * 64 + b_n] = bv;
        __syncthreads();
#pragma unroll
        for (int k = 0; k < 16; ++k) {
            float4 a4v = *(const float4*)&As[k * 64 + ty * 4];
            float4 b4v = *(const float4*)&Bs[k * 64 + tx * 4];
            acc[0][0] = fmaf(a4v.x, b4v.x, acc[0][0]);
            acc[0][1] = fmaf(a4v.x, b4v.y, acc[0][1]);
            acc[0][2] = fmaf(a4v.x, b4v.z, acc[0][2]);
            acc[0][3] = fmaf(a4v.x, b4v.w, acc[0][3]);
            acc[1][0] = fmaf(a4v.y, b4v.x, acc[1][0]);
            acc[1][1] = fmaf(a4v.y, b4v.y, acc[1][1]);
            acc[1][2] = fmaf(a4v.y, b4v.z, acc[1][2]);
            acc[1][3] = fmaf(a4v.y, b4v.w, acc[1][3]);
            acc[2][0] = fmaf(a4v.z, b4v.x, acc[2][0]);
            acc[2][1] = fmaf(a4v.z, b4v.y, acc[2][1]);
            acc[2][2] = fmaf(a4v.z, b4v.z, acc[2][2]);
            acc[2][3] = fmaf(a4v.z, b4v.w, acc[2][3]);
            acc[3][0] = fmaf(a4v.w, b4v.x, acc[3][0]);
            acc[3][1] = fmaf(a4v.w, b4v.y, acc[3][1]);
            acc[3][2] = fmaf(a4v.w, b4v.z, acc[3][2]);
            acc[3][3] = fmaf(a4v.w, b4v.w, acc[3][3]);
        }
    }
#pragma unroll
    for (int i = 0; i < 4; ++i) {
        int mm = m0 + ty * 4 + i;
#pragma unroll
        for (int j = 0; j < 4; ++j) {
            int nn = n0 + tx * 4 + j;
            if (nn < Nn) {
                float v = acc[i][j];
                if (bias) v += bias[nn];
                if (do_tanh) v = ftanh(v);
                C[(long)mm * Nn + nn] = v;
            }
        }
    }
}

// ---------------- K3a: per-atom Ei + Etot + dh0g ----------------
__global__ __launch_bounds__(256) void k3a(
    const float* __restrict__ fh0, const float* __restrict__ fh1,
    const float* __restrict__ fw1, const float* __restrict__ fw2, const float* __restrict__ fb2,
    float* __restrict__ out, float* __restrict__ dh0g)
{
    int n = blockIdx.x;
    int t = n / NA;
    int tid = threadIdx.x;
    __shared__ float u1s[FHD];
    __shared__ float red[256];

    float p = 0.f;
    if (tid < FHD) {
        float h1v = fh1[(long)n * FHD + tid];
        float w2v = fw2[t * FHD + tid];
        p = h1v * w2v;
        u1s[tid] = w2v * (1.f - h1v * h1v);
    }
    red[tid] = p;
    __syncthreads();
    for (int off = 128; off > 0; off >>= 1) {
        if (tid < off) red[tid] += red[tid + off];
        __syncthreads();
    }
    if (tid == 0) {
        float e = red[0] + fb2[t];
        out[OUT_EI + n] = e;
        atomicAdd(out, e);
    }
    if (tid < FHD) {
        const float* w1row = fw1 + (long)t * FHD * FHD + (long)tid * FHD;
        float acc = 0.f;
        for (int o = 0; o < FHD; ++o) acc = fmaf(u1s[o], w1row[o], acc);
        float h0v = fh0[(long)n * FHD + tid];
        dh0g[(long)n * FHD + tid] = acc * (1.f - h0v * h0v);
    }
}

// ---------------- K3b: per-atom P, g-major float4 [n][g][c] (INV200 folded) ----------------
__global__ __launch_bounds__(256) void k3b(
    const float* __restrict__ Q, const float* __restrict__ xa, float* __restrict__ P4)
{
    int n = blockIdx.x;
    int tid = threadIdx.x;
    __shared__ float qs[DD];
    __shared__ float xs[400];
    for (int i = tid; i < DD; i += 256) qs[i] = Q[(long)n * DD + i];
    for (int i = tid; i < 400; i += 256) xs[i] = xa[(long)n * 400 + i];
    __syncthreads();
    for (int i = tid; i < 400; i += 256) {
        int c = i / GD, g = i % GD;
        float acc = 0.f;
        for (int m = 0; m < M2D; ++m) acc = fmaf(qs[g * M2D + m], xs[c * GD + m], acc);
        if (g < M2D) {
            for (int g2 = 0; g2 < GD; ++g2) acc = fmaf(qs[g2 * M2D + g], xs[c * GD + g2], acc);
        }
        P4[((long)n * GD + g) * 4 + c] = acc * INV200;
    }
}

// ---------------- K4: per-(atom,neighbor) backward via table, forces, virial ----------------
#define AB 8
__global__ __launch_bounds__(256, 2) void k4(
    const float* __restrict__ Ri, const float* __restrict__ dfeat,
    const float* __restrict__ ImageDR, const int* __restrict__ list_neigh,
    const float4* __restrict__ P4ws, float* __restrict__ out)
{
    __shared__ float4 Ps[AB * GD];   // per-atom P4[g]; wave lanes share atom -> broadcast reads
    __shared__ float facc[AB * 3];
    __shared__ float vacc[6];

    int tid = threadIdx.x;
    int blk = blockIdx.x;
    long base_item = (long)blk * (AB * JN);

    if (tid < AB * 3) facc[tid] = 0.f;
    if (tid < 6) vacc[tid] = 0.f;
    for (int i = tid; i < AB * GD; i += 256) Ps[i] = P4ws[(long)blk * (AB * GD) + i];
    __syncthreads();

    float v00 = 0.f, v01 = 0.f, v02 = 0.f, v11 = 0.f, v12 = 0.f, v22 = 0.f;

    for (int it = 0; it < (AB * JN + 255) / 256; ++it) {
        int idx = it * 256 + tid;
        if (idx < AB * JN) {
            int nl = idx / JN;
            int j = idx - nl * JN;
            long item = base_item + idx;
            float4 a = ((const float4*)Ri)[item];
            int tau = j / MAXNB;

            const float2 *row0, *row1;
            float c00, c01, c10, c11, d00, d10, d11;
            hermite_basis(a.x, tau, &row0, &row1, c00, c01, c10, c11, d00, d10, d11);

            const float4* Pn = Ps + nl * GD;
            float dEda0 = 0.f, dEda1 = 0.f, dEda2 = 0.f, dEda3 = 0.f;
            float ds = 0.f;

#pragma unroll 4
            for (int g = 0; g < GD; ++g) {
                float2 r0 = row0[g], r1 = row1[g];
                float G = r0.x * c00 + r1.x * c01 + r0.y * c10 + r1.y * c11;
                float dG = (r0.x - r1.x) * d00 + r0.y * d10 + r1.y * d11;
                float4 p = Pn[g];
                float dEdG = p.x * a.x + p.y * a.y + p.z * a.z + p.w * a.w;
                dEda0 = fmaf(p.x, G, dEda0);
                dEda1 = fmaf(p.y, G, dEda1);
                dEda2 = fmaf(p.z, G, dEda2);
                dEda3 = fmaf(p.w, G, dEda3);
                ds = fmaf(dEdG, dG, ds);
            }
            dEda0 += ds;

            const float* df = dfeat + item * 12;
            float dEdx0 = dEda0 * df[0] + dEda1 * df[3] + dEda2 * df[6] + dEda3 * df[9];
            float dEdx1 = dEda0 * df[1] + dEda1 * df[4] + dEda2 * df[7] + dEda3 * df[10];
            float dEdx2 = dEda0 * df[2] + dEda1 * df[5] + dEda2 * df[8] + dEda3 * df[11];

            atomicAdd(&facc[nl * 3 + 0], dEdx0);
            atomicAdd(&facc[nl * 3 + 1], dEdx1);
            atomicAdd(&facc[nl * 3 + 2], dEdx2);

            int ln = list_neigh[item];
            if (ln > 0) {
                int ii = ln - 1;
                if (ii > NATOMS - 1) ii = NATOMS - 1;
                atomicAdd(&out[OUT_F + ii * 3 + 0], dEdx0);
                atomicAdd(&out[OUT_F + ii * 3 + 1], dEdx1);
                atomicAdd(&out[OUT_F + ii * 3 + 2], dEdx2);
                const float* im = ImageDR + item * 3;
                v00 = fmaf(im[0], dEdx0, v00);
                v01 = fmaf(im[0], dEdx1, v01);
                v02 = fmaf(im[0], dEdx2, v02);
                v11 = fmaf(im[1], dEdx1, v11);
                v12 = fmaf(im[1], dEdx2, v12);
                v22 = fmaf(im[2], dEdx2, v22);
            }
        }
    }

#pragma unroll
    for (int off = 32; off > 0; off >>= 1) {
        v00 += __shfl_down(v00, off);
        v01 += __shfl_down(v01, off);
        v02 += __shfl_down(v02, off);
        v11 += __shfl_down(v11, off);
        v12 += __shfl_down(v12, off);
        v22 += __shfl_down(v22, off);
    }
    if ((tid & 63) == 0) {
        atomicAdd(&vacc[0], v00);
        atomicAdd(&vacc[1], v01);
        atomicAdd(&vacc[2], v02);
        atomicAdd(&vacc[3], v11);
        atomicAdd(&vacc[4], v12);
        atomicAdd(&vacc[5], v22);
    }
    __syncthreads();
    if (tid < AB * 3) {
        int nl = tid / 3, c = tid % 3;
        atomicAdd(&out[OUT_F + (blk * AB + nl) * 3 + c], -facc[tid]);
    }
    if (tid < 9) {
        const int vmap[9] = {0, 1, 2, 1, 3, 4, 2, 4, 5};
        atomicAdd(&out[OUT_V + tid], vacc[vmap[tid]]);
    }
}

extern "C" void kernel_launch(void* const* d_in, const int* in_sizes, int n_in,
                              void* d_out, int out_size, void* d_ws, size_t ws_size,
                              hipStream_t stream) {
    const float* Ri = (const float*)d_in[0];
    const float* dfeat = (const float*)d_in[1];
    const float* ImageDR = (const float*)d_in[2];
    const float* tv = (const float*)d_in[3];
    const float* ew0 = (const float*)d_in[4];
    const float* eb0 = (const float*)d_in[5];
    const float* ew1 = (const float*)d_in[6];
    const float* eb1 = (const float*)d_in[7];
    const float* ew2 = (const float*)d_in[8];
    const float* eb2 = (const float*)d_in[9];
    const float* fw0 = (const float*)d_in[10];
    const float* fb0 = (const float*)d_in[11];
    const float* fw1 = (const float*)d_in[12];
    const float* fb1 = (const float*)d_in[13];
    const float* fw2 = (const float*)d_in[14];
    const float* fb2 = (const float*)d_in[15];
    const int* list_neigh = (const int*)d_in[16];

    float* out = (float*)d_out;
    float* ws = (float*)d_ws;
    float* drQ = ws + WS_DRQ;
    float* xa = ws + WS_XA;
    float* P = ws + WS_P;
    float* fh0 = ws + WS_FH0;
    float* fh1 = ws + WS_FH1;
    float* dh0g = ws + WS_DH0G;
    float* fw0T = ws + WS_FW0T;

    hipMemsetAsync(d_out, 0, (size_t)out_size * sizeof(float), stream);

    k_setup<<<(NTYPES * DD * FHD + 255) / 256, 256, 0, stream>>>(fw0, fw0T);
    k_table<<<(NTYPES * NK + 63) / 64, 64, 0, stream>>>(ew0, eb0, ew1, eb1, ew2, eb2, tv);

    k1_emb<<<NATOMS, 256, 0, stream>>>(Ri, drQ, xa);

    // fit forward: fh0 = tanh(dr @ fw0 + fb0), fh1 = tanh(fh0 @ fw1 + fb1)
    gemm_kernel<<<dim3(4, 32, 2), 256, 0, stream>>>(drQ, fw0, fb0, fh0,
        2048, 240, 1600, 2048L * 1600, 1600L * 240, 240L, 2048L * 240, 1);
    gemm_kernel<<<dim3(4, 32, 2), 256, 0, stream>>>(fh0, fw1, fb1, fh1,
        2048, 240, 240, 2048L * 240, 240L * 240, 240L, 2048L * 240, 1);

    k3a<<<NATOMS, 256, 0, stream>>>(fh0, fh1, fw1, fw2, fb2, out, dh0g);

    // Q = dh0g @ fw0^T  (overwrites dr buffer)
    gemm_kernel<<<dim3(25, 32, 2), 256, 0, stream>>>(dh0g, fw0T, nullptr, drQ,
        2048, 1600, 240, 2048L * 240, 240L * 1600, 0L, 2048L * 1600, 0);

    k3b<<<NATOMS, 256, 0, stream>>>(drQ, xa, P);

    k4<<<NATOMS / AB, 256, 0, stream>>>(Ri, dfeat, ImageDR, list_neigh,
        (const float4*)P, out);
}

// Round 5
// 801.735 us; speedup vs baseline: 1.3792x; 1.3792x over previous
//
#include <hip/hip_runtime.h>

// Problem constants
#define NATOMS 4096
#define NTYPES 2
#define NA 2048
#define MAXNB 100
#define JN 200          // neighbors per atom
#define TFD 4
#define E0 25           // emb hidden 0
#define E1 50           // emb hidden 1
#define GD 100          // GDIM
#define M2D 16
#define DD 1600         // D = M2*GDIM
#define FHD 240
#define INV200 (1.0f/200.0f)

// Output layout (floats): Etot@0 (1), Ei@1 (4096), F@4097 (12288), Virial@16385 (9)
#define OUT_EI 1
#define OUT_F 4097
#define OUT_V 16385

// Workspace layout (floats)
#define WS_DRQ 0L                 // 4096*1600  (dr, later overwritten by Q)
#define WS_XA 6553600L            // 4096*400
#define WS_P 8192000L             // 4096*400  (g-major float4: [n][g][c])
#define WS_FH0 9830400L           // 4096*240
#define WS_FH1 10813440L          // 4096*240
#define WS_DH0G 11796480L         // 4096*240
#define WS_FW0T 12779520L         // 2*240*1600

// G(s) lookup table. Embedding-net input is [s, temb(type)] with temb constant
// per type, so G is a 1-D function of s per type. Cubic Hermite, 2048 knots.
// Packed float4 per (type,knot,g): (G_i, dG_i, G_{i+1}, dG_{i+1}) -> one 16B
// load per g in the hot loops. Entry NK-1's (z,w) is never read (i<=NK-2).
#define NK 2048
#define S_MIN (-8.0f)
#define S_H 0.0078125f      // 16/2048
#define S_INVH 128.0f
__device__ float4 g_tab4[NTYPES * NK * GD];
__device__ float2 g_th1[NTYPES * NK * E1];   // (h1, v1=dh1/ds) per (t,knot,l)

__device__ __forceinline__ float ftanh(float x) {
    float ax = fabsf(x);
    float e = __expf(-2.0f * ax);
    float t = (1.0f - e) / (1.0f + e);
    return copysignf(t, x);
}

// ---------------- setup: transpose fw0 ----------------
__global__ void k_setup(const float* __restrict__ fw0, float* __restrict__ fw0T) {
    int idx = blockIdx.x * 256 + threadIdx.x;
    if (idx < NTYPES * DD * FHD) {
        int t = idx / (DD * FHD);
        int r = idx % (DD * FHD);
        int o = r / DD, d = r % DD;
        fw0T[idx] = fw0[(long)t * DD * FHD + (long)d * FHD + o];
    }
}

// ---------------- table stage 1: h1/v1 per (type, knot) ----------------
__global__ __launch_bounds__(256) void k_table_h(
    const float* __restrict__ ew0, const float* __restrict__ eb0,
    const float* __restrict__ ew1, const float* __restrict__ eb1,
    const float* __restrict__ tv)
{
    int idx = blockIdx.x * 256 + threadIdx.x;
    if (idx >= NTYPES * NK) return;
    int t = idx / NK, i = idx % NK;
    float s = S_MIN + (float)i * S_H;

    float h0[E0], t0[E0];
#pragma unroll
    for (int k = 0; k < E0; ++k) {
        float c = eb0[k];
#pragma unroll
        for (int f = 0; f < TFD; ++f) c = fmaf(tv[t * TFD + f], ew0[(1 + f) * E0 + k], c);
        float h = ftanh(fmaf(s, ew0[k], c));
        h0[k] = h;
        t0[k] = (1.f - h * h) * ew0[k];
    }
#pragma unroll 2
    for (int l = 0; l < E1; ++l) {
        float acc = eb1[l], dacc = 0.f;
#pragma unroll
        for (int k = 0; k < E0; ++k) {
            float w = ew1[k * E1 + l];
            acc = fmaf(h0[k], w, acc);
            dacc = fmaf(t0[k], w, dacc);
        }
        float h = ftanh(acc);
        g_th1[(long)idx * E1 + l] = make_float2(h, (1.f - h * h) * dacc);
    }
}

// ---------------- table stage 2: one thread per (type, knot, g) ----------------
__global__ __launch_bounds__(256) void k_table_g(
    const float* __restrict__ ew2, const float* __restrict__ eb2)
{
    long idx = (long)blockIdx.x * 256 + threadIdx.x;
    if (idx >= (long)NTYPES * NK * GD) return;
    int g = idx % GD;
    long ti = idx / GD;          // t*NK + i
    int i = ti % NK;

    const float2* hv = g_th1 + ti * E1;
    float acc = eb2[g], dacc = 0.f;
#pragma unroll 5
    for (int l = 0; l < E1; ++l) {
        float2 x = hv[l];
        float w = ew2[l * GD + g];
        acc = fmaf(x.x, w, acc);
        dacc = fmaf(x.y, w, dacc);
    }
    float G = ftanh(acc);
    float dv = (1.f - G * G) * dacc;

    float2* f2 = (float2*)g_tab4;
    long e = ti * GD + g;
    f2[2 * e] = make_float2(G, dv);                 // (x,y) of entry i
    if (i > 0) f2[2 * (e - GD) + 1] = make_float2(G, dv);  // (z,w) of entry i-1
}

// Hermite basis; returns row pointer into packed table for (tau, knot i).
__device__ __forceinline__ const float4* hermite4(float s, int tau,
    float& c00, float& c01, float& c10, float& c11,
    float& d00, float& d10, float& d11)
{
    float x = (s - S_MIN) * S_INVH;
    x = fminf(fmaxf(x, 0.f), (float)(NK - 1) - 1e-3f);
    int i = (int)x;
    float u = x - (float)i;
    float um = 1.f - u;
    c00 = (1.f + 2.f * u) * um * um;
    c01 = u * u * (3.f - 2.f * u);
    c10 = S_H * u * um * um;
    c11 = S_H * u * u * (u - 1.f);
    d00 = (6.f * u * u - 6.f * u) * S_INVH;
    d10 = fmaf(3.f * u, u, fmaf(-4.f, u, 1.f));
    d11 = fmaf(3.f * u, u, -2.f * u);
    return g_tab4 + (long)(tau * NK + i) * GD;
}

// ---------------- K1: per-atom G (table) -> xa -> dr ----------------
#define GCH 25
__global__ __launch_bounds__(256) void k1_emb(
    const float* __restrict__ Ri,
    float* __restrict__ dr_ws, float* __restrict__ xa_ws)
{
    __shared__ float a4s[JN * 4];
    __shared__ float Gs[GCH * 201];
    __shared__ float xas[4 * GD];
    __shared__ float red[256];

    int tid = threadIdx.x;
    int n = blockIdx.x;

    float4 a = make_float4(0.f, 0.f, 0.f, 0.f);
    const float4* row = nullptr;
    float c00 = 0.f, c01 = 0.f, c10 = 0.f, c11 = 0.f, d00, d10, d11;
    if (tid < JN) {
        a = ((const float4*)Ri)[(long)n * JN + tid];
        ((float4*)a4s)[tid] = a;
        row = hermite4(a.x, tid / MAXNB, c00, c01, c10, c11, d00, d10, d11);
    }
    __syncthreads();

    int gl_r = tid % GCH;
    int c_r = (tid / GCH) % 4;
    int jh_r = tid / 100;

    for (int cc = 0; cc < 4; ++cc) {
        int g0 = cc * GCH;
        if (tid < JN) {
#pragma unroll
            for (int gl = 0; gl < GCH; ++gl) {
                float4 r = row[g0 + gl];
                Gs[gl * 201 + tid] = r.x * c00 + r.z * c01 + r.y * c10 + r.w * c11;
            }
        }
        __syncthreads();
        float s_ = 0.f;
        if (tid < JN) {
            const float* grow = &Gs[gl_r * 201 + jh_r * 100];
            const float* arow = &a4s[jh_r * 400 + c_r];
            for (int jj = 0; jj < 100; ++jj)
                s_ = fmaf(arow[jj * 4], grow[jj], s_);
        }
        red[tid] = s_;
        __syncthreads();
        if (tid < 100) {
            int c = tid / GCH, gl = tid % GCH;
            xas[c * GD + g0 + gl] = (red[tid] + red[tid + 100]) * INV200;
        }
        __syncthreads();
    }

    for (int i = tid; i < 4 * GD; i += 256) xa_ws[(long)n * 400 + i] = xas[i];
    for (int i = tid; i < DD; i += 256) {
        int gg = i / M2D, m = i % M2D;
        float v = 0.f;
#pragma unroll
        for (int c = 0; c < 4; ++c) v = fmaf(xas[c * GD + gg], xas[c * GD + m], v);
        dr_ws[(long)n * DD + i] = v;
    }
}

// ---------------- generic tiled fp32 GEMM: C = act(A@B + bias), per-type batch z ----------------
__global__ __launch_bounds__(256) void gemm_kernel(
    const float* __restrict__ Ab, const float* __restrict__ Bb,
    const float* __restrict__ biasb, float* __restrict__ Cb,
    int M, int Nn, int K, long sA, long sB, long sBias, long sC, int do_tanh)
{
    int t = blockIdx.z;
    const float* A = Ab + (long)t * sA;
    const float* B = Bb + (long)t * sB;
    const float* bias = biasb ? (biasb + (long)t * sBias) : nullptr;
    float* C = Cb + (long)t * sC;

    __shared__ float As[16 * 64];
    __shared__ float Bs[16 * 64];

    int tid = threadIdx.x;
    int n0 = blockIdx.x * 64;
    int m0 = blockIdx.y * 64;
    int tx = tid % 16, ty = tid / 16;

    float acc[4][4];
#pragma unroll
    for (int i = 0; i < 4; ++i)
#pragma unroll
        for (int j = 0; j < 4; ++j) acc[i][j] = 0.f;

    int a_m = tid / 4;
    int a_k = (tid % 4) * 4;
    int b_k = tid / 16;
    int b_n = (tid % 16) * 4;

    for (int k0 = 0; k0 < K; k0 += 16) {
        float4 av = *(const float4*)&A[(long)(m0 + a_m) * K + k0 + a_k];
        float4 bv = make_float4(0.f, 0.f, 0.f, 0.f);
        if (n0 + b_n < Nn) bv = *(const float4*)&B[(long)(k0 + b_k) * Nn + n0 + b_n];
        __syncthreads();
        As[(a_k + 0) * 64 + a_m] = av.x;
        As[(a_k + 1) * 64 + a_m] = av.y;
        As[(a_k + 2) * 64 + a_m] = av.z;
        As[(a_k + 3) * 64 + a_m] = av.w;
        *(float4*)&Bs[b_k * 64 + b_n] = bv;
        __syncthreads();
#pragma unroll
        for (int k = 0; k < 16; ++k) {
            float4 a4v = *(const float4*)&As[k * 64 + ty * 4];
            float4 b4v = *(const float4*)&Bs[k * 64 + tx * 4];
            acc[0][0] = fmaf(a4v.x, b4v.x, acc[0][0]);
            acc[0][1] = fmaf(a4v.x, b4v.y, acc[0][1]);
            acc[0][2] = fmaf(a4v.x, b4v.z, acc[0][2]);
            acc[0][3] = fmaf(a4v.x, b4v.w, acc[0][3]);
            acc[1][0] = fmaf(a4v.y, b4v.x, acc[1][0]);
            acc[1][1] = fmaf(a4v.y, b4v.y, acc[1][1]);
            acc[1][2] = fmaf(a4v.y, b4v.z, acc[1][2]);
            acc[1][3] = fmaf(a4v.y, b4v.w, acc[1][3]);
            acc[2][0] = fmaf(a4v.z, b4v.x, acc[2][0]);
            acc[2][1] = fmaf(a4v.z, b4v.y, acc[2][1]);
            acc[2][2] = fmaf(a4v.z, b4v.z, acc[2][2]);
            acc[2][3] = fmaf(a4v.z, b4v.w, acc[2][3]);
            acc[3][0] = fmaf(a4v.w, b4v.x, acc[3][0]);
            acc[3][1] = fmaf(a4v.w, b4v.y, acc[3][1]);
            acc[3][2] = fmaf(a4v.w, b4v.z, acc[3][2]);
            acc[3][3] = fmaf(a4v.w, b4v.w, acc[3][3]);
        }
    }
#pragma unroll
    for (int i = 0; i < 4; ++i) {
        int mm = m0 + ty * 4 + i;
#pragma unroll
        for (int j = 0; j < 4; ++j) {
            int nn = n0 + tx * 4 + j;
            if (nn < Nn) {
                float v = acc[i][j];
                if (bias) v += bias[nn];
                if (do_tanh) v = ftanh(v);
                C[(long)mm * Nn + nn] = v;
            }
        }
    }
}

// ---------------- K3a: per-atom Ei + Etot + dh0g ----------------
__global__ __launch_bounds__(256) void k3a(
    const float* __restrict__ fh0, const float* __restrict__ fh1,
    const float* __restrict__ fw1, const float* __restrict__ fw2, const float* __restrict__ fb2,
    float* __restrict__ out, float* __restrict__ dh0g)
{
    int n = blockIdx.x;
    int t = n / NA;
    int tid = threadIdx.x;
    __shared__ float u1s[FHD];
    __shared__ float red[256];

    float p = 0.f;
    if (tid < FHD) {
        float h1v = fh1[(long)n * FHD + tid];
        float w2v = fw2[t * FHD + tid];
        p = h1v * w2v;
        u1s[tid] = w2v * (1.f - h1v * h1v);
    }
    red[tid] = p;
    __syncthreads();
    for (int off = 128; off > 0; off >>= 1) {
        if (tid < off) red[tid] += red[tid + off];
        __syncthreads();
    }
    if (tid == 0) {
        float e = red[0] + fb2[t];
        out[OUT_EI + n] = e;
        atomicAdd(out, e);
    }
    if (tid < FHD) {
        const float* w1row = fw1 + (long)t * FHD * FHD + (long)tid * FHD;
        float acc = 0.f;
        for (int o = 0; o < FHD; ++o) acc = fmaf(u1s[o], w1row[o], acc);
        float h0v = fh0[(long)n * FHD + tid];
        dh0g[(long)n * FHD + tid] = acc * (1.f - h0v * h0v);
    }
}

// ---------------- K3b: per-atom P, g-major float4 [n][g][c] (INV200 folded) ----------------
__global__ __launch_bounds__(256) void k3b(
    const float* __restrict__ Q, const float* __restrict__ xa, float* __restrict__ P4)
{
    int n = blockIdx.x;
    int tid = threadIdx.x;
    __shared__ float qs[DD];
    __shared__ float xs[400];
    for (int i = tid; i < DD; i += 256) qs[i] = Q[(long)n * DD + i];
    for (int i = tid; i < 400; i += 256) xs[i] = xa[(long)n * 400 + i];
    __syncthreads();
    for (int i = tid; i < 400; i += 256) {
        int c = i / GD, g = i % GD;
        float acc = 0.f;
        for (int m = 0; m < M2D; ++m) acc = fmaf(qs[g * M2D + m], xs[c * GD + m], acc);
        if (g < M2D) {
            for (int g2 = 0; g2 < GD; ++g2) acc = fmaf(qs[g2 * M2D + g], xs[c * GD + g2], acc);
        }
        P4[((long)n * GD + g) * 4 + c] = acc * INV200;
    }
}

// ---------------- K4: per-(atom,neighbor) backward via table, forces, virial ----------------
// AB=2 -> 2048 blocks (8 blocks/CU) so L2 table-gather latency is hidden.
#define AB 2
__global__ __launch_bounds__(256) void k4(
    const float* __restrict__ Ri, const float* __restrict__ dfeat,
    const float* __restrict__ ImageDR, const int* __restrict__ list_neigh,
    const float4* __restrict__ P4ws, float* __restrict__ out)
{
    __shared__ float4 Ps[AB * GD];   // per-atom P4[g]; lanes of a wave share atom -> broadcast
    __shared__ float facc[AB * 3];
    __shared__ float vacc[6];

    int tid = threadIdx.x;
    int blk = blockIdx.x;
    long base_item = (long)blk * (AB * JN);

    if (tid < AB * 3) facc[tid] = 0.f;
    if (tid < 6) vacc[tid] = 0.f;
    for (int i = tid; i < AB * GD; i += 256) Ps[i] = P4ws[(long)blk * (AB * GD) + i];
    __syncthreads();

    float v00 = 0.f, v01 = 0.f, v02 = 0.f, v11 = 0.f, v12 = 0.f, v22 = 0.f;

    for (int it = 0; it < (AB * JN + 255) / 256; ++it) {
        int idx = it * 256 + tid;
        if (idx < AB * JN) {
            int nl = idx / JN;
            int j = idx - nl * JN;
            long item = base_item + idx;
            float4 a = ((const float4*)Ri)[item];
            int tau = j / MAXNB;

            float c00, c01, c10, c11, d00, d10, d11;
            const float4* row = hermite4(a.x, tau, c00, c01, c10, c11, d00, d10, d11);

            const float4* Pn = Ps + nl * GD;
            float dEda0 = 0.f, dEda1 = 0.f, dEda2 = 0.f, dEda3 = 0.f;
            float ds = 0.f;

#pragma unroll 4
            for (int g = 0; g < GD; ++g) {
                float4 r = row[g];
                float G = r.x * c00 + r.z * c01 + r.y * c10 + r.w * c11;
                float dG = (r.x - r.z) * d00 + r.y * d10 + r.w * d11;
                float4 p = Pn[g];
                float dEdG = p.x * a.x + p.y * a.y + p.z * a.z + p.w * a.w;
                dEda0 = fmaf(p.x, G, dEda0);
                dEda1 = fmaf(p.y, G, dEda1);
                dEda2 = fmaf(p.z, G, dEda2);
                dEda3 = fmaf(p.w, G, dEda3);
                ds = fmaf(dEdG, dG, ds);
            }
            dEda0 += ds;

            const float* df = dfeat + item * 12;
            float dEdx0 = dEda0 * df[0] + dEda1 * df[3] + dEda2 * df[6] + dEda3 * df[9];
            float dEdx1 = dEda0 * df[1] + dEda1 * df[4] + dEda2 * df[7] + dEda3 * df[10];
            float dEdx2 = dEda0 * df[2] + dEda1 * df[5] + dEda2 * df[8] + dEda3 * df[11];

            atomicAdd(&facc[nl * 3 + 0], dEdx0);
            atomicAdd(&facc[nl * 3 + 1], dEdx1);
            atomicAdd(&facc[nl * 3 + 2], dEdx2);

            int ln = list_neigh[item];
            if (ln > 0) {
                int ii = ln - 1;
                if (ii > NATOMS - 1) ii = NATOMS - 1;
                atomicAdd(&out[OUT_F + ii * 3 + 0], dEdx0);
                atomicAdd(&out[OUT_F + ii * 3 + 1], dEdx1);
                atomicAdd(&out[OUT_F + ii * 3 + 2], dEdx2);
                const float* im = ImageDR + item * 3;
                v00 = fmaf(im[0], dEdx0, v00);
                v01 = fmaf(im[0], dEdx1, v01);
                v02 = fmaf(im[0], dEdx2, v02);
                v11 = fmaf(im[1], dEdx1, v11);
                v12 = fmaf(im[1], dEdx2, v12);
                v22 = fmaf(im[2], dEdx2, v22);
            }
        }
    }

#pragma unroll
    for (int off = 32; off > 0; off >>= 1) {
        v00 += __shfl_down(v00, off);
        v01 += __shfl_down(v01, off);
        v02 += __shfl_down(v02, off);
        v11 += __shfl_down(v11, off);
        v12 += __shfl_down(v12, off);
        v22 += __shfl_down(v22, off);
    }
    if ((tid & 63) == 0) {
        atomicAdd(&vacc[0], v00);
        atomicAdd(&vacc[1], v01);
        atomicAdd(&vacc[2], v02);
        atomicAdd(&vacc[3], v11);
        atomicAdd(&vacc[4], v12);
        atomicAdd(&vacc[5], v22);
    }
    __syncthreads();
    if (tid < AB * 3) {
        int nl = tid / 3, c = tid % 3;
        atomicAdd(&out[OUT_F + (blk * AB + nl) * 3 + c], -facc[tid]);
    }
    if (tid < 9) {
        const int vmap[9] = {0, 1, 2, 1, 3, 4, 2, 4, 5};
        atomicAdd(&out[OUT_V + tid], vacc[vmap[tid]]);
    }
}

extern "C" void kernel_launch(void* const* d_in, const int* in_sizes, int n_in,
                              void* d_out, int out_size, void* d_ws, size_t ws_size,
                              hipStream_t stream) {
    const float* Ri = (const float*)d_in[0];
    const float* dfeat = (const float*)d_in[1];
    const float* ImageDR = (const float*)d_in[2];
    const float* tv = (const float*)d_in[3];
    const float* ew0 = (const float*)d_in[4];
    const float* eb0 = (const float*)d_in[5];
    const float* ew1 = (const float*)d_in[6];
    const float* eb1 = (const float*)d_in[7];
    const float* ew2 = (const float*)d_in[8];
    const float* eb2 = (const float*)d_in[9];
    const float* fw0 = (const float*)d_in[10];
    const float* fb0 = (const float*)d_in[11];
    const float* fw1 = (const float*)d_in[12];
    const float* fb1 = (const float*)d_in[13];
    const float* fw2 = (const float*)d_in[14];
    const float* fb2 = (const float*)d_in[15];
    const int* list_neigh = (const int*)d_in[16];

    float* out = (float*)d_out;
    float* ws = (float*)d_ws;
    float* drQ = ws + WS_DRQ;
    float* xa = ws + WS_XA;
    float* P = ws + WS_P;
    float* fh0 = ws + WS_FH0;
    float* fh1 = ws + WS_FH1;
    float* dh0g = ws + WS_DH0G;
    float* fw0T = ws + WS_FW0T;

    hipMemsetAsync(d_out, 0, (size_t)out_size * sizeof(float), stream);

    k_setup<<<(NTYPES * DD * FHD + 255) / 256, 256, 0, stream>>>(fw0, fw0T);
    k_table_h<<<(NTYPES * NK + 255) / 256, 256, 0, stream>>>(ew0, eb0, ew1, eb1, tv);
    k_table_g<<<(NTYPES * NK * GD + 255) / 256, 256, 0, stream>>>(ew2, eb2);

    k1_emb<<<NATOMS, 256, 0, stream>>>(Ri, drQ, xa);

    // fit forward: fh0 = tanh(dr @ fw0 + fb0), fh1 = tanh(fh0 @ fw1 + fb1)
    gemm_kernel<<<dim3(4, 32, 2), 256, 0, stream>>>(drQ, fw0, fb0, fh0,
        2048, 240, 1600, 2048L * 1600, 1600L * 240, 240L, 2048L * 240, 1);
    gemm_kernel<<<dim3(4, 32, 2), 256, 0, stream>>>(fh0, fw1, fb1, fh1,
        2048, 240, 240, 2048L * 240, 240L * 240, 240L, 2048L * 240, 1);

    k3a<<<NATOMS, 256, 0, stream>>>(fh0, fh1, fw1, fw2, fb2, out, dh0g);

    // Q = dh0g @ fw0^T  (overwrites dr buffer)
    gemm_kernel<<<dim3(25, 32, 2), 256, 0, stream>>>(dh0g, fw0T, nullptr, drQ,
        2048, 1600, 240, 2048L * 240, 240L * 1600, 0L, 2048L * 1600, 0);

    k3b<<<NATOMS, 256, 0, stream>>>(drQ, xa, P);

    k4<<<NATOMS / AB, 256, 0, stream>>>(Ri, dfeat, ImageDR, list_neigh,
        (const float4*)P, out);
}